// Round 1
// baseline (222.905 us; speedup 1.0000x reference)
//
#include <hip/hip_runtime.h>
#include <math.h>

// Problem sizes (fixed by the reference)
static constexpr int B_  = 4;
static constexpr int TQ  = 128;
static constexpr int TK  = 512;
static constexpr int NN  = 1024;   // key_size n
static constexpr int QS  = 1024;
static constexpr int VS  = 1024;
static constexpr int OS  = 1024;

#define K2F    2.8853900817779268f   // 2*log2(e)
#define LOG2EF 1.4426950408889634f

// ---------------------------------------------------------------------------
// [B] Ek = exp2(keys * 2*log2e)  == e^{2*keys}, elementwise, float4
// ---------------------------------------------------------------------------
__global__ __launch_bounds__(256) void exp_kernel(const float* __restrict__ x,
                                                  float* __restrict__ y) {
    int i = blockIdx.x * 256 + threadIdx.x;     // float4 index
    float4 v = ((const float4*)x)[i];
    v.x = exp2f(v.x * K2F);
    v.y = exp2f(v.y * K2F);
    v.z = exp2f(v.z * K2F);
    v.w = exp2f(v.w * K2F);
    ((float4*)y)[i] = v;
}

// ---------------------------------------------------------------------------
// [A] Ea = exp2((query @ Wq^T + bq) * 2*log2e)   (NT GEMM, 64x64 tile, 4x4/thr)
// A: [M,K] row-major, Bw: [Nn,K] row-major
// ---------------------------------------------------------------------------
__global__ __launch_bounds__(256) void gemm_nt_exp_kernel(
    const float* __restrict__ A, const float* __restrict__ Bw,
    const float* __restrict__ bias, float* __restrict__ E,
    int M, int Nn, int K)
{
    __shared__ float As[16][68];
    __shared__ float Bs[16][68];
    const int tid = threadIdx.x;
    const int tx = tid & 15, ty = tid >> 4;
    const int m0 = blockIdx.y * 64, n0 = blockIdx.x * 64;
    const int lr = tid >> 2;          // 0..63
    const int lk = (tid & 3) * 4;     // 0,4,8,12
    float acc[4][4] = {};
    for (int kb = 0; kb < K; kb += 16) {
        float4 av = *(const float4*)(A  + (size_t)(m0 + lr) * K + kb + lk);
        float4 bv = *(const float4*)(Bw + (size_t)(n0 + lr) * K + kb + lk);
        As[lk+0][lr] = av.x; As[lk+1][lr] = av.y; As[lk+2][lr] = av.z; As[lk+3][lr] = av.w;
        Bs[lk+0][lr] = bv.x; Bs[lk+1][lr] = bv.y; Bs[lk+2][lr] = bv.z; Bs[lk+3][lr] = bv.w;
        __syncthreads();
        #pragma unroll
        for (int kc = 0; kc < 16; ++kc) {
            float a[4], b[4];
            #pragma unroll
            for (int i = 0; i < 4; ++i) a[i] = As[kc][ty*4+i];
            #pragma unroll
            for (int j = 0; j < 4; ++j) b[j] = Bs[kc][tx*4+j];
            #pragma unroll
            for (int i = 0; i < 4; ++i)
                #pragma unroll
                for (int j = 0; j < 4; ++j)
                    acc[i][j] = fmaf(a[i], b[j], acc[i][j]);
        }
        __syncthreads();
    }
    #pragma unroll
    for (int i = 0; i < 4; ++i) {
        int m = m0 + ty*4 + i;
        #pragma unroll
        for (int j = 0; j < 4; ++j) {
            int n = n0 + tx*4 + j;
            E[(size_t)m*Nn + n] = exp2f((acc[i][j] + bias[n]) * K2F);
        }
    }
}

// ---------------------------------------------------------------------------
// [C] Sp[nh][bq][k] = sum_{n in half nh} w[n] * rcp(1 + Ea[bq,n]*Ek[bk,n])
// 32q x 32k tile, 2x2 per thread, n split in 2 halves for occupancy.
// tanh(s) = 1 - 2/(1+e^{2s}); softmax shift-invariance kills the constants.
// ---------------------------------------------------------------------------
__global__ __launch_bounds__(256) void score_partial_kernel(
    const float* __restrict__ Ea,   // [B*TQ, NN]
    const float* __restrict__ Ek,   // [B*TK, NN]
    const float* __restrict__ watt, // [NN]
    float* __restrict__ Sp)         // [2][B*TQ, TK]
{
    __shared__ float EaS[32][34];
    __shared__ float EkS[32][34];
    __shared__ float wS[32];
    const int tid = threadIdx.x;
    const int tx = tid & 15, ty = tid >> 4;
    const int kt = blockIdx.x;          // 0..15
    const int qt = blockIdx.y;          // 0..3
    const int bz = blockIdx.z;          // 0..7
    const int b = bz >> 1, nh = bz & 1;
    const int qrow0 = b*TQ + qt*32;
    const int krow0 = b*TK + kt*32;
    const int lr = tid >> 3;            // 0..31
    const int ln = (tid & 7) * 4;       // 0..28
    float acc[2][2] = {};
    const int nend = nh*512 + 512;
    for (int nb = nh*512; nb < nend; nb += 32) {
        float4 av = *(const float4*)(Ea + (size_t)(qrow0 + lr)*NN + nb + ln);
        float4 kv = *(const float4*)(Ek + (size_t)(krow0 + lr)*NN + nb + ln);
        EaS[ln+0][lr]=av.x; EaS[ln+1][lr]=av.y; EaS[ln+2][lr]=av.z; EaS[ln+3][lr]=av.w;
        EkS[ln+0][lr]=kv.x; EkS[ln+1][lr]=kv.y; EkS[ln+2][lr]=kv.z; EkS[ln+3][lr]=kv.w;
        if (tid < 32) wS[tid] = watt[nb + tid];
        __syncthreads();
        #pragma unroll
        for (int n = 0; n < 32; ++n) {
            float wn  = wS[n];
            float ea0 = EaS[n][ty*2],  ea1 = EaS[n][ty*2+1];
            float ek0 = EkS[n][tx*2],  ek1 = EkS[n][tx*2+1];
            acc[0][0] = fmaf(wn, __builtin_amdgcn_rcpf(fmaf(ea0, ek0, 1.0f)), acc[0][0]);
            acc[0][1] = fmaf(wn, __builtin_amdgcn_rcpf(fmaf(ea0, ek1, 1.0f)), acc[0][1]);
            acc[1][0] = fmaf(wn, __builtin_amdgcn_rcpf(fmaf(ea1, ek0, 1.0f)), acc[1][0]);
            acc[1][1] = fmaf(wn, __builtin_amdgcn_rcpf(fmaf(ea1, ek1, 1.0f)), acc[1][1]);
        }
        __syncthreads();
    }
    #pragma unroll
    for (int i = 0; i < 2; ++i) {
        int q = qt*32 + ty*2 + i;
        #pragma unroll
        for (int j = 0; j < 2; ++j) {
            int k = kt*32 + tx*2 + j;
            Sp[(size_t)nh*(B_*TQ*TK) + (size_t)(b*TQ + q)*TK + k] = acc[i][j];
        }
    }
}

// ---------------------------------------------------------------------------
// [D] softmax over k of (-2*(S0+S1)); one wave per (b,q) row; writes output 1
// ---------------------------------------------------------------------------
__global__ __launch_bounds__(256) void softmax_kernel(
    const float* __restrict__ Sp, float* __restrict__ P)
{
    const int lane = threadIdx.x & 63;
    const int wid  = threadIdx.x >> 6;
    const int row  = blockIdx.x * 4 + wid;      // 0..511
    const float* s0 = Sp + (size_t)row * TK;
    const float* s1 = Sp + (size_t)(B_*TQ*TK) + (size_t)row * TK;
    float v[8];
    float m = -3.4e38f;
    #pragma unroll
    for (int j = 0; j < 8; ++j) {
        int k = lane + j*64;
        v[j] = -2.0f * (s0[k] + s1[k]);
        m = fmaxf(m, v[j]);
    }
    #pragma unroll
    for (int off = 32; off; off >>= 1) m = fmaxf(m, __shfl_xor(m, off, 64));
    float sum = 0.f;
    #pragma unroll
    for (int j = 0; j < 8; ++j) { v[j] = exp2f((v[j] - m) * LOG2EF); sum += v[j]; }
    #pragma unroll
    for (int off = 32; off; off >>= 1) sum += __shfl_xor(sum, off, 64);
    float inv = 1.0f / sum;
    #pragma unroll
    for (int j = 0; j < 8; ++j)
        P[(size_t)row * TK + lane + j*64] = v[j] * inv;
}

// ---------------------------------------------------------------------------
// [E] context = P @ values   (NN GEMM per batch; 32m x 64v tile, 2x4/thr)
// ---------------------------------------------------------------------------
__global__ __launch_bounds__(256) void pv_kernel(
    const float* __restrict__ P,    // [B*TQ, TK]
    const float* __restrict__ V,    // [B, TK, VS]
    float* __restrict__ C)          // [B*TQ, VS]
{
    __shared__ float As[32][34];    // [kc][m]
    __shared__ float Bs[32][68];    // [kc][v]
    const int tid = threadIdx.x;
    const int tx = tid & 15, ty = tid >> 4;
    const int m0 = blockIdx.y * 32;
    const int v0 = blockIdx.x * 64;
    const int b  = m0 / TQ;
    float acc[2][4] = {};
    for (int kb = 0; kb < TK; kb += 32) {
        {
            int r = tid >> 3, c0 = (tid & 7) * 4;
            float4 av = *(const float4*)(P + (size_t)(m0 + r)*TK + kb + c0);
            As[c0+0][r]=av.x; As[c0+1][r]=av.y; As[c0+2][r]=av.z; As[c0+3][r]=av.w;
        }
        {
            int kc = tid >> 4, vv = (tid & 15) * 4;
            #pragma unroll
            for (int r = 0; r < 2; ++r) {
                float4 bv = *(const float4*)(V + ((size_t)b*TK + kb + kc + r*16)*VS + v0 + vv);
                *(float4*)&Bs[kc + r*16][vv] = bv;
            }
        }
        __syncthreads();
        #pragma unroll
        for (int kc = 0; kc < 32; ++kc) {
            float a0 = As[kc][ty*2], a1 = As[kc][ty*2+1];
            float b0 = Bs[kc][tx*4+0], b1 = Bs[kc][tx*4+1];
            float b2 = Bs[kc][tx*4+2], b3 = Bs[kc][tx*4+3];
            acc[0][0] = fmaf(a0,b0,acc[0][0]); acc[0][1] = fmaf(a0,b1,acc[0][1]);
            acc[0][2] = fmaf(a0,b2,acc[0][2]); acc[0][3] = fmaf(a0,b3,acc[0][3]);
            acc[1][0] = fmaf(a1,b0,acc[1][0]); acc[1][1] = fmaf(a1,b1,acc[1][1]);
            acc[1][2] = fmaf(a1,b2,acc[1][2]); acc[1][3] = fmaf(a1,b3,acc[1][3]);
        }
        __syncthreads();
    }
    #pragma unroll
    for (int i = 0; i < 2; ++i) {
        int m = m0 + ty*2 + i;
        #pragma unroll
        for (int j = 0; j < 4; ++j)
            C[(size_t)m*VS + v0 + tx*4 + j] = acc[i][j];
    }
}

// ---------------------------------------------------------------------------
// [F] out = tanh([query|context] @ Wout^T + bout)   (NT GEMM, K=2048)
// ---------------------------------------------------------------------------
__global__ __launch_bounds__(256) void out_gemm_kernel(
    const float* __restrict__ Q,    // [B*TQ, QS]
    const float* __restrict__ Cx,   // [B*TQ, VS]
    const float* __restrict__ W,    // [OS, QS+VS]
    const float* __restrict__ bias, // [OS]
    float* __restrict__ out)        // [B*TQ, OS]
{
    __shared__ float As[16][68];
    __shared__ float Bs[16][68];
    const int tid = threadIdx.x;
    const int tx = tid & 15, ty = tid >> 4;
    const int m0 = blockIdx.y * 64, n0 = blockIdx.x * 64;
    const int lr = tid >> 2;
    const int lk = (tid & 3) * 4;
    float acc[4][4] = {};
    for (int kb = 0; kb < QS + VS; kb += 16) {
        const float* Asrc = (kb < QS)
            ? (Q  + (size_t)(m0 + lr)*QS + kb + lk)
            : (Cx + (size_t)(m0 + lr)*VS + (kb - QS) + lk);
        float4 av = *(const float4*)Asrc;
        float4 bv = *(const float4*)(W + (size_t)(n0 + lr)*(QS+VS) + kb + lk);
        As[lk+0][lr] = av.x; As[lk+1][lr] = av.y; As[lk+2][lr] = av.z; As[lk+3][lr] = av.w;
        Bs[lk+0][lr] = bv.x; Bs[lk+1][lr] = bv.y; Bs[lk+2][lr] = bv.z; Bs[lk+3][lr] = bv.w;
        __syncthreads();
        #pragma unroll
        for (int kc = 0; kc < 16; ++kc) {
            float a[4], bb[4];
            #pragma unroll
            for (int i = 0; i < 4; ++i) a[i]  = As[kc][ty*4+i];
            #pragma unroll
            for (int j = 0; j < 4; ++j) bb[j] = Bs[kc][tx*4+j];
            #pragma unroll
            for (int i = 0; i < 4; ++i)
                #pragma unroll
                for (int j = 0; j < 4; ++j)
                    acc[i][j] = fmaf(a[i], bb[j], acc[i][j]);
        }
        __syncthreads();
    }
    #pragma unroll
    for (int i = 0; i < 4; ++i) {
        int m = m0 + ty*4 + i;
        #pragma unroll
        for (int j = 0; j < 4; ++j) {
            int n = n0 + tx*4 + j;
            out[(size_t)m*OS + n] = tanhf(acc[i][j] + bias[n]);
        }
    }
}

// ---------------------------------------------------------------------------
extern "C" void kernel_launch(void* const* d_in, const int* in_sizes, int n_in,
                              void* d_out, int out_size, void* d_ws, size_t ws_size,
                              hipStream_t stream)
{
    const float* query  = (const float*)d_in[0];   // [4,128,1024]
    const float* keys   = (const float*)d_in[1];   // [4,512,1024]
    const float* values = (const float*)d_in[2];   // [4,512,1024]
    const float* Wq     = (const float*)d_in[3];   // [1024,1024]
    const float* bq     = (const float*)d_in[4];   // [1024]
    const float* watt   = (const float*)d_in[5];   // [1024]
    // d_in[6] = b_att: dropped (softmax shift-invariance)
    const float* Wout   = (const float*)d_in[7];   // [1024,2048]
    const float* bout   = (const float*)d_in[8];   // [1024]

    float* out = (float*)d_out;                    // 524288 floats
    float* P   = out + (size_t)B_*TQ*OS;           // 262144 floats (output 1)

    float* ws  = (float*)d_ws;
    float* Ea  = ws;                               // 524288
    float* Ek  = Ea + (size_t)B_*TQ*NN;            // 2097152
    float* Sp  = Ek + (size_t)B_*TK*NN;            // 2*262144
    float* Cx  = Sp + (size_t)2*B_*TQ*TK;          // 524288
    // total ws use: 14,680,064 bytes

    // [B] Ek = e^{2*keys}: 2097152 floats = 524288 float4 -> 2048 blocks
    exp_kernel<<<dim3(2048), dim3(256), 0, stream>>>(keys, Ek);
    // [A] Ea = e^{2*(query@Wq^T+bq)}
    gemm_nt_exp_kernel<<<dim3(16, 8), dim3(256), 0, stream>>>(
        query, Wq, bq, Ea, B_*TQ, NN, QS);
    // [C] partial scores
    score_partial_kernel<<<dim3(16, 4, 8), dim3(256), 0, stream>>>(Ea, Ek, watt, Sp);
    // [D] softmax -> P (output 1)
    softmax_kernel<<<dim3(128), dim3(256), 0, stream>>>(Sp, P);
    // [E] context = P @ values
    pv_kernel<<<dim3(16, 16), dim3(256), 0, stream>>>(P, values, Cx);
    // [F] out = tanh([query|context] @ Wout^T + bout) (output 0)
    out_gemm_kernel<<<dim3(16, 8), dim3(256), 0, stream>>>(query, Cx, Wout, bout, out);
}

// Round 2
// 138.045 us; speedup vs baseline: 1.6147x; 1.6147x over previous
//
#include <hip/hip_runtime.h>
#include <math.h>

// Problem sizes (fixed by the reference)
static constexpr int B_  = 4;
static constexpr int TQ  = 128;
static constexpr int TK  = 512;
static constexpr int NN  = 1024;   // key_size n
static constexpr int QS  = 1024;
static constexpr int VS  = 1024;
static constexpr int OS  = 1024;

#define K2F    2.8853900817779268f   // 2*log2(e)
#define LOG2EF 1.4426950408889634f

// ---------------------------------------------------------------------------
// [B] Ek = e^{2*keys}, elementwise, float4
// ---------------------------------------------------------------------------
__global__ __launch_bounds__(256) void exp_kernel(const float* __restrict__ x,
                                                  float* __restrict__ y) {
    int i = blockIdx.x * 256 + threadIdx.x;     // float4 index
    float4 v = ((const float4*)x)[i];
    v.x = exp2f(v.x * K2F);
    v.y = exp2f(v.y * K2F);
    v.z = exp2f(v.z * K2F);
    v.w = exp2f(v.w * K2F);
    ((float4*)y)[i] = v;
}

// ---------------------------------------------------------------------------
// Shared 64x64x16 f32 tile inner: float4 LDS reads, 16 FMA per 2 ds_read_b128
// ---------------------------------------------------------------------------
__device__ __forceinline__ void tile16(const float (*As)[68], const float (*Bs)[68],
                                       int ty, int tx, float acc[4][4]) {
    #pragma unroll
    for (int kc = 0; kc < 16; ++kc) {
        float4 a = *(const float4*)&As[kc][ty*4];
        float4 b = *(const float4*)&Bs[kc][tx*4];
        float av[4] = {a.x, a.y, a.z, a.w};
        float bv[4] = {b.x, b.y, b.z, b.w};
        #pragma unroll
        for (int i = 0; i < 4; ++i)
            #pragma unroll
            for (int j = 0; j < 4; ++j)
                acc[i][j] = fmaf(av[i], bv[j], acc[i][j]);
    }
}

// ---------------------------------------------------------------------------
// [A] partial NT GEMM: Cp[kz][m][n] = sum_{k in chunk kz} A[m,k]*Bw[n,k]
// 64x64 tile, 4x4/thread, K-split via blockIdx.z
// ---------------------------------------------------------------------------
__global__ __launch_bounds__(256) void gemm_nt_split_kernel(
    const float* __restrict__ A, const float* __restrict__ Bw,
    float* __restrict__ Cp, int M, int Nn, int K, int kchunk)
{
    __shared__ alignas(16) float As[16][68];
    __shared__ alignas(16) float Bs[16][68];
    const int tid = threadIdx.x;
    const int tx = tid & 15, ty = tid >> 4;
    const int m0 = blockIdx.y * 64, n0 = blockIdx.x * 64;
    const int kz = blockIdx.z;
    const int k0 = kz * kchunk, k1 = k0 + kchunk;
    const int lr = tid >> 2;          // 0..63
    const int lk = (tid & 3) * 4;     // 0,4,8,12
    float acc[4][4] = {};
    const float* Ap = A  + (size_t)(m0 + lr) * K + lk;
    const float* Bp = Bw + (size_t)(n0 + lr) * K + lk;
    for (int kb = k0; kb < k1; kb += 16) {
        float4 av = *(const float4*)(Ap + kb);
        float4 bv = *(const float4*)(Bp + kb);
        As[lk+0][lr] = av.x; As[lk+1][lr] = av.y; As[lk+2][lr] = av.z; As[lk+3][lr] = av.w;
        Bs[lk+0][lr] = bv.x; Bs[lk+1][lr] = bv.y; Bs[lk+2][lr] = bv.z; Bs[lk+3][lr] = bv.w;
        __syncthreads();
        tile16(As, Bs, ty, tx, acc);
        __syncthreads();
    }
    float* o = Cp + (size_t)kz * M * Nn;
    #pragma unroll
    for (int i = 0; i < 4; ++i) {
        int m = m0 + ty*4 + i;
        #pragma unroll
        for (int j = 0; j < 4; ++j)
            o[(size_t)m*Nn + n0 + tx*4 + j] = acc[i][j];
    }
}

// ---------------------------------------------------------------------------
// [A2] Ea = exp2((p0+p1+bq)*2log2e)
// ---------------------------------------------------------------------------
__global__ __launch_bounds__(256) void exp_combine_kernel(
    const float* __restrict__ Ap, const float* __restrict__ bias,
    float* __restrict__ E)
{
    int i = blockIdx.x * 256 + threadIdx.x;          // float4 index (131072 total)
    float4 p0 = ((const float4*)Ap)[i];
    float4 p1 = ((const float4*)(Ap + (size_t)B_*TQ*NN))[i];
    float4 bb = ((const float4*)bias)[i & 255];
    float4 r;
    r.x = exp2f((p0.x + p1.x + bb.x) * K2F);
    r.y = exp2f((p0.y + p1.y + bb.y) * K2F);
    r.z = exp2f((p0.z + p1.z + bb.z) * K2F);
    r.w = exp2f((p0.w + p1.w + bb.w) * K2F);
    ((float4*)E)[i] = r;
}

// ---------------------------------------------------------------------------
// [C] Sp[nh][bq][k] = sum_{n in half nh} w[n] * rcp(1 + Ea[bq,n]*Ek[bk,n])
// tanh(s) = 1 - 2/(1+e^{2s}); softmax shift-invariance kills the constants.
// ---------------------------------------------------------------------------
__global__ __launch_bounds__(256) void score_partial_kernel(
    const float* __restrict__ Ea,   // [B*TQ, NN]
    const float* __restrict__ Ek,   // [B*TK, NN]
    const float* __restrict__ watt, // [NN]
    float* __restrict__ Sp)         // [2][B*TQ, TK]
{
    __shared__ float EaS[32][34];
    __shared__ float EkS[32][34];
    __shared__ float wS[32];
    const int tid = threadIdx.x;
    const int tx = tid & 15, ty = tid >> 4;
    const int kt = blockIdx.x;          // 0..15
    const int qt = blockIdx.y;          // 0..3
    const int bz = blockIdx.z;          // 0..7
    const int b = bz >> 1, nh = bz & 1;
    const int qrow0 = b*TQ + qt*32;
    const int krow0 = b*TK + kt*32;
    const int lr = tid >> 3;            // 0..31
    const int ln = (tid & 7) * 4;       // 0..28
    float acc[2][2] = {};
    const int nend = nh*512 + 512;
    for (int nb = nh*512; nb < nend; nb += 32) {
        float4 av = *(const float4*)(Ea + (size_t)(qrow0 + lr)*NN + nb + ln);
        float4 kv = *(const float4*)(Ek + (size_t)(krow0 + lr)*NN + nb + ln);
        EaS[ln+0][lr]=av.x; EaS[ln+1][lr]=av.y; EaS[ln+2][lr]=av.z; EaS[ln+3][lr]=av.w;
        EkS[ln+0][lr]=kv.x; EkS[ln+1][lr]=kv.y; EkS[ln+2][lr]=kv.z; EkS[ln+3][lr]=kv.w;
        if (tid < 32) wS[tid] = watt[nb + tid];
        __syncthreads();
        #pragma unroll
        for (int n = 0; n < 32; ++n) {
            float wn  = wS[n];
            float ea0 = EaS[n][ty*2],  ea1 = EaS[n][ty*2+1];
            float ek0 = EkS[n][tx*2],  ek1 = EkS[n][tx*2+1];
            acc[0][0] = fmaf(wn, __builtin_amdgcn_rcpf(fmaf(ea0, ek0, 1.0f)), acc[0][0]);
            acc[0][1] = fmaf(wn, __builtin_amdgcn_rcpf(fmaf(ea0, ek1, 1.0f)), acc[0][1]);
            acc[1][0] = fmaf(wn, __builtin_amdgcn_rcpf(fmaf(ea1, ek0, 1.0f)), acc[1][0]);
            acc[1][1] = fmaf(wn, __builtin_amdgcn_rcpf(fmaf(ea1, ek1, 1.0f)), acc[1][1]);
        }
        __syncthreads();
    }
    #pragma unroll
    for (int i = 0; i < 2; ++i) {
        int q = qt*32 + ty*2 + i;
        #pragma unroll
        for (int j = 0; j < 2; ++j) {
            int k = kt*32 + tx*2 + j;
            Sp[(size_t)nh*(B_*TQ*TK) + (size_t)(b*TQ + q)*TK + k] = acc[i][j];
        }
    }
}

// ---------------------------------------------------------------------------
// [D] softmax over k of (-2*(S0+S1)); one wave per (b,q) row; writes output 1
// ---------------------------------------------------------------------------
__global__ __launch_bounds__(256) void softmax_kernel(
    const float* __restrict__ Sp, float* __restrict__ P)
{
    const int lane = threadIdx.x & 63;
    const int wid  = threadIdx.x >> 6;
    const int row  = blockIdx.x * 4 + wid;      // 0..511
    const float* s0 = Sp + (size_t)row * TK;
    const float* s1 = Sp + (size_t)(B_*TQ*TK) + (size_t)row * TK;
    float v[8];
    float m = -3.4e38f;
    #pragma unroll
    for (int j = 0; j < 8; ++j) {
        int k = lane + j*64;
        v[j] = -2.0f * (s0[k] + s1[k]);
        m = fmaxf(m, v[j]);
    }
    #pragma unroll
    for (int off = 32; off; off >>= 1) m = fmaxf(m, __shfl_xor(m, off, 64));
    float sum = 0.f;
    #pragma unroll
    for (int j = 0; j < 8; ++j) { v[j] = exp2f((v[j] - m) * LOG2EF); sum += v[j]; }
    #pragma unroll
    for (int off = 32; off; off >>= 1) sum += __shfl_xor(sum, off, 64);
    float inv = 1.0f / sum;
    #pragma unroll
    for (int j = 0; j < 8; ++j)
        P[(size_t)row * TK + lane + j*64] = v[j] * inv;
}

// ---------------------------------------------------------------------------
// [E] partial NN GEMM: Ep[kz][m][v] = sum_{k in chunk} P[m,k]*V[b,k,v]
// 64x64 tile, 4x4/thread, K-split 2
// ---------------------------------------------------------------------------
__global__ __launch_bounds__(256) void pv_split_kernel(
    const float* __restrict__ P,    // [B*TQ, TK]
    const float* __restrict__ V,    // [B, TK, VS]
    float* __restrict__ Ep)         // [2][B*TQ, VS]
{
    __shared__ alignas(16) float As[16][68];
    __shared__ alignas(16) float Bs[16][68];
    const int tid = threadIdx.x;
    const int tx = tid & 15, ty = tid >> 4;
    const int m0 = blockIdx.y * 64;
    const int v0 = blockIdx.x * 64;
    const int kz = blockIdx.z;
    const int b  = m0 >> 7;             // 128 rows per batch
    const int lr = tid >> 2, lk = (tid & 3) * 4;        // A staging
    const int br = tid >> 4, bc = (tid & 15) * 4;       // B staging
    float acc[4][4] = {};
    const int k0 = kz * (TK/2), k1 = k0 + (TK/2);
    for (int kb = k0; kb < k1; kb += 16) {
        float4 av = *(const float4*)(P + (size_t)(m0 + lr)*TK + kb + lk);
        As[lk+0][lr] = av.x; As[lk+1][lr] = av.y; As[lk+2][lr] = av.z; As[lk+3][lr] = av.w;
        float4 bv = *(const float4*)(V + ((size_t)b*TK + kb + br)*VS + v0 + bc);
        *(float4*)&Bs[br][bc] = bv;
        __syncthreads();
        tile16(As, Bs, ty, tx, acc);
        __syncthreads();
    }
    float* o = Ep + (size_t)kz * (B_*TQ*VS);
    #pragma unroll
    for (int i = 0; i < 4; ++i) {
        int m = m0 + ty*4 + i;
        #pragma unroll
        for (int j = 0; j < 4; ++j)
            o[(size_t)m*VS + v0 + tx*4 + j] = acc[i][j];
    }
}

__global__ __launch_bounds__(256) void add_combine_kernel(
    const float* __restrict__ Ep, float* __restrict__ C)
{
    int i = blockIdx.x * 256 + threadIdx.x;          // float4 index
    float4 p0 = ((const float4*)Ep)[i];
    float4 p1 = ((const float4*)(Ep + (size_t)B_*TQ*VS))[i];
    float4 r = {p0.x+p1.x, p0.y+p1.y, p0.z+p1.z, p0.w+p1.w};
    ((float4*)C)[i] = r;
}

// ---------------------------------------------------------------------------
// [F] partial out GEMM: Fp[kz][m][n] over K=2048 split 4 (chunks 0,1: Q; 2,3: Cx)
// ---------------------------------------------------------------------------
__global__ __launch_bounds__(256) void out_gemm_split_kernel(
    const float* __restrict__ Q,    // [B*TQ, QS]
    const float* __restrict__ Cx,   // [B*TQ, VS]
    const float* __restrict__ W,    // [OS, QS+VS]
    float* __restrict__ Fp)         // [4][B*TQ, OS]
{
    __shared__ alignas(16) float As[16][68];
    __shared__ alignas(16) float Bs[16][68];
    const int tid = threadIdx.x;
    const int tx = tid & 15, ty = tid >> 4;
    const int m0 = blockIdx.y * 64, n0 = blockIdx.x * 64;
    const int kz = blockIdx.z;                       // 0..3, chunk of 512
    const int lr = tid >> 2, lk = (tid & 3) * 4;
    const float* Asrc = (kz < 2) ? (Q  + (size_t)(m0+lr)*QS + kz*512 + lk)
                                 : (Cx + (size_t)(m0+lr)*VS + (kz-2)*512 + lk);
    const float* Bp = W + (size_t)(n0+lr)*(QS+VS) + kz*512 + lk;
    float acc[4][4] = {};
    for (int kb = 0; kb < 512; kb += 16) {
        float4 av = *(const float4*)(Asrc + kb);
        float4 bv = *(const float4*)(Bp + kb);
        As[lk+0][lr] = av.x; As[lk+1][lr] = av.y; As[lk+2][lr] = av.z; As[lk+3][lr] = av.w;
        Bs[lk+0][lr] = bv.x; Bs[lk+1][lr] = bv.y; Bs[lk+2][lr] = bv.z; Bs[lk+3][lr] = bv.w;
        __syncthreads();
        tile16(As, Bs, ty, tx, acc);
        __syncthreads();
    }
    float* o = Fp + (size_t)kz * (B_*TQ*OS);
    #pragma unroll
    for (int i = 0; i < 4; ++i) {
        int m = m0 + ty*4 + i;
        #pragma unroll
        for (int j = 0; j < 4; ++j)
            o[(size_t)m*OS + n0 + tx*4 + j] = acc[i][j];
    }
}

__global__ __launch_bounds__(256) void tanh_combine_kernel(
    const float* __restrict__ Fp, const float* __restrict__ bias,
    float* __restrict__ out)
{
    int i = blockIdx.x * 256 + threadIdx.x;          // float4 index
    const size_t S = (size_t)B_*TQ*OS;
    float4 p0 = ((const float4*)Fp)[i];
    float4 p1 = ((const float4*)(Fp + S))[i];
    float4 p2 = ((const float4*)(Fp + 2*S))[i];
    float4 p3 = ((const float4*)(Fp + 3*S))[i];
    float4 bb = ((const float4*)bias)[i & 255];
    float4 r;
    r.x = tanhf(p0.x + p1.x + p2.x + p3.x + bb.x);
    r.y = tanhf(p0.y + p1.y + p2.y + p3.y + bb.y);
    r.z = tanhf(p0.z + p1.z + p2.z + p3.z + bb.z);
    r.w = tanhf(p0.w + p1.w + p2.w + p3.w + bb.w);
    ((float4*)out)[i] = r;
}

// ---------------------------------------------------------------------------
extern "C" void kernel_launch(void* const* d_in, const int* in_sizes, int n_in,
                              void* d_out, int out_size, void* d_ws, size_t ws_size,
                              hipStream_t stream)
{
    const float* query  = (const float*)d_in[0];   // [4,128,1024]
    const float* keys   = (const float*)d_in[1];   // [4,512,1024]
    const float* values = (const float*)d_in[2];   // [4,512,1024]
    const float* Wq     = (const float*)d_in[3];   // [1024,1024]
    const float* bq     = (const float*)d_in[4];   // [1024]
    const float* watt   = (const float*)d_in[5];   // [1024]
    // d_in[6] = b_att: dropped (softmax shift-invariance)
    const float* Wout   = (const float*)d_in[7];   // [1024,2048]
    const float* bout   = (const float*)d_in[8];   // [1024]

    float* out = (float*)d_out;                    // 524288 floats (output 0)
    float* P   = out + (size_t)B_*TQ*OS;           // 262144 floats (output 1)

    // ws layout (floats), peak 14,680,064 B — same as last passing round:
    //   [0 .. 2097152)        Ek      -> later reused: Ep (2x524288), then Fp (4x524288)
    //   [2097152 .. 2621440)  Ea
    //   [2621440 .. 3145728)  Sp      -> earlier reused (with Cx region) as Ap (2x524288)
    //   [3145728 .. 3670016)  Cx
    float* ws  = (float*)d_ws;
    float* Ek  = ws;
    float* Ea  = ws + 2097152;
    float* Sp  = ws + 2621440;
    float* Cx  = ws + 3145728;
    float* Ap  = ws + 2621440;   // alias Sp+Cx (dead until score kernel)
    float* Ep  = ws;             // alias Ek (dead after score kernel)
    float* Fp  = ws;             // alias Ek/Ep (dead after add_combine)

    // [B] Ek = e^{2*keys}
    exp_kernel<<<dim3(2048), dim3(256), 0, stream>>>(keys, Ek);
    // [A] partial q@Wq^T, K-split 2
    gemm_nt_split_kernel<<<dim3(16, 8, 2), dim3(256), 0, stream>>>(
        query, Wq, Ap, B_*TQ, NN, QS, 512);
    // [A2] Ea = e^{2*(sum+bq)}
    exp_combine_kernel<<<dim3(512), dim3(256), 0, stream>>>(Ap, bq, Ea);
    // [C] partial scores (overwrites Ap region — Ap is dead)
    score_partial_kernel<<<dim3(16, 4, 8), dim3(256), 0, stream>>>(Ea, Ek, watt, Sp);
    // [D] softmax -> P (output 1)
    softmax_kernel<<<dim3(128), dim3(256), 0, stream>>>(Sp, P);
    // [E] context partials (overwrites Ek region — Ek is dead)
    pv_split_kernel<<<dim3(16, 8, 2), dim3(256), 0, stream>>>(P, values, Ep);
    add_combine_kernel<<<dim3(512), dim3(256), 0, stream>>>(Ep, Cx);
    // [F] out partials, K-split 4 (overwrites Ep region — Ep is dead)
    out_gemm_split_kernel<<<dim3(16, 8, 4), dim3(256), 0, stream>>>(query, Cx, Wout, Fp);
    tanh_combine_kernel<<<dim3(512), dim3(256), 0, stream>>>(Fp, bout, out);
}

// Round 3
// 111.977 us; speedup vs baseline: 1.9906x; 1.2328x over previous
//
#include <hip/hip_runtime.h>
#include <math.h>

static constexpr int B_  = 4;
static constexpr int TQ  = 128;
static constexpr int TK  = 512;
static constexpr int NN  = 1024;
static constexpr int QS  = 1024;
static constexpr int VS  = 1024;
static constexpr int OS  = 1024;

#define K2F    2.8853900817779268f   // 2*log2(e)
#define LOG2EF 1.4426950408889634f

typedef __attribute__((ext_vector_type(8))) short bf16x8;
typedef __attribute__((ext_vector_type(4))) float f32x4;

#define MFMA16(a,b,c) __builtin_amdgcn_mfma_f32_16x16x32_bf16((a),(b),(c),0,0,0)

// f32 -> bf16 round-to-nearest-even
__device__ __forceinline__ ushort bf16_rne(float x) {
    uint u = __float_as_uint(x);
    u += 0x7FFFu + ((u >> 16) & 1u);
    return (ushort)(u >> 16);
}
// split f32 into hi+lo bf16 (a ~= hi + lo, rel err ~2^-17)
__device__ __forceinline__ void split2(float x, ushort& h, ushort& l) {
    ushort hh = bf16_rne(x);
    float hv = __uint_as_float((uint)hh << 16);
    h = hh;
    l = bf16_rne(x - hv);
}

// ---------------------------------------------------------------------------
// cvt: f32[n] -> hi bf16[n], lo bf16[n]; 4 elems/thread
// ---------------------------------------------------------------------------
__global__ __launch_bounds__(256) void cvt_split_kernel(
    const float* __restrict__ x, ushort* __restrict__ h, ushort* __restrict__ l)
{
    int i = blockIdx.x * 256 + threadIdx.x;      // float4 index
    float4 v = ((const float4*)x)[i];
    ushort4 hh, ll;
    split2(v.x, hh.x, ll.x); split2(v.y, hh.y, ll.y);
    split2(v.z, hh.z, ll.z); split2(v.w, hh.w, ll.w);
    ((ushort4*)h)[i] = hh;
    ((ushort4*)l)[i] = ll;
}

// ---------------------------------------------------------------------------
// V [b][k=512][v=1024] -> Vt hi/lo [b][v=1024][k=512]  (64x64 LDS transpose)
// ---------------------------------------------------------------------------
__global__ __launch_bounds__(256) void cvt_transpose_v_kernel(
    const float* __restrict__ V, ushort* __restrict__ Th, ushort* __restrict__ Tl)
{
    __shared__ float tile[64][65];
    const int b = blockIdx.z, k0 = blockIdx.y * 64, v0 = blockIdx.x * 64;
    const int t = threadIdx.x;
    const float* src = V + ((size_t)b*TK + k0)*VS + v0;
    #pragma unroll
    for (int p = 0; p < 4; ++p) {
        int r = (t >> 4) + p*16, c = (t & 15) * 4;
        float4 vv = *(const float4*)(src + (size_t)r*VS + c);
        tile[r][c] = vv.x; tile[r][c+1] = vv.y; tile[r][c+2] = vv.z; tile[r][c+3] = vv.w;
    }
    __syncthreads();
    ushort* dh = Th + (size_t)b*(VS*TK) + (size_t)v0*TK + k0;
    ushort* dl = Tl + (size_t)b*(VS*TK) + (size_t)v0*TK + k0;
    #pragma unroll
    for (int p = 0; p < 4; ++p) {
        int vr = (t >> 4) + p*16, kc = (t & 15) * 4;
        ushort4 hh, ll;
        split2(tile[kc+0][vr], hh.x, ll.x);
        split2(tile[kc+1][vr], hh.y, ll.y);
        split2(tile[kc+2][vr], hh.z, ll.z);
        split2(tile[kc+3][vr], hh.w, ll.w);
        *(ushort4*)(dh + (size_t)vr*TK + kc) = hh;
        *(ushort4*)(dl + (size_t)vr*TK + kc) = ll;
    }
}

// ---------------------------------------------------------------------------
// Generic split-bf16 NT MFMA GEMM, M=512 fixed.
// A hi/lo [512,lda], B hi/lo [Nrows,ldb] (+ per-batch stride), out partial f32.
// 64x64 block tile, 4 waves x (32x32), K-split via blockIdx.z.
// ---------------------------------------------------------------------------
__global__ __launch_bounds__(256) void mfma_nt_kernel(
    const ushort* __restrict__ Ah, const ushort* __restrict__ Al,
    const ushort* __restrict__ Bh, const ushort* __restrict__ Bl,
    float* __restrict__ Cp, int lda, int ldb, int Nout, int kchunk, int bstride)
{
    __shared__ alignas(16) ushort lA[2][64][40];   // [hi/lo][row][k], 80B rows
    __shared__ alignas(16) ushort lB[2][64][40];
    const int t = threadIdx.x;
    const int m0 = blockIdx.y * 64, n0 = blockIdx.x * 64, kz = blockIdx.z;
    const int k0 = kz * kchunk;
    const int batch = m0 >> 7;
    const ushort* bhp = Bh + (size_t)batch * bstride;
    const ushort* blp = Bl + (size_t)batch * bstride;
    const int srow = t >> 2, skc = (t & 3) * 8;
    const int lane = t & 63, w = t >> 6;
    const int wm = (w >> 1) * 32, wn = (w & 1) * 32;
    const int fr = lane & 15, fg = (lane >> 4) * 8;

    f32x4 acc00 = {0,0,0,0}, acc01 = {0,0,0,0}, acc10 = {0,0,0,0}, acc11 = {0,0,0,0};

    for (int kb = k0; kb < k0 + kchunk; kb += 32) {
        uint4 va_h = *(const uint4*)(Ah  + (size_t)(m0+srow)*lda + kb + skc);
        uint4 va_l = *(const uint4*)(Al  + (size_t)(m0+srow)*lda + kb + skc);
        uint4 vb_h = *(const uint4*)(bhp + (size_t)(n0+srow)*ldb + kb + skc);
        uint4 vb_l = *(const uint4*)(blp + (size_t)(n0+srow)*ldb + kb + skc);
        *(uint4*)&lA[0][srow][skc] = va_h;
        *(uint4*)&lA[1][srow][skc] = va_l;
        *(uint4*)&lB[0][srow][skc] = vb_h;
        *(uint4*)&lB[1][srow][skc] = vb_l;
        __syncthreads();
        bf16x8 ah0 = *(const bf16x8*)&lA[0][wm + fr     ][fg];
        bf16x8 ah1 = *(const bf16x8*)&lA[0][wm + 16 + fr][fg];
        bf16x8 al0 = *(const bf16x8*)&lA[1][wm + fr     ][fg];
        bf16x8 al1 = *(const bf16x8*)&lA[1][wm + 16 + fr][fg];
        bf16x8 bh0 = *(const bf16x8*)&lB[0][wn + fr     ][fg];
        bf16x8 bh1 = *(const bf16x8*)&lB[0][wn + 16 + fr][fg];
        bf16x8 bl0 = *(const bf16x8*)&lB[1][wn + fr     ][fg];
        bf16x8 bl1 = *(const bf16x8*)&lB[1][wn + 16 + fr][fg];
        acc00 = MFMA16(ah0, bh0, acc00);
        acc00 = MFMA16(al0, bh0, acc00);
        acc00 = MFMA16(ah0, bl0, acc00);
        acc01 = MFMA16(ah0, bh1, acc01);
        acc01 = MFMA16(al0, bh1, acc01);
        acc01 = MFMA16(ah0, bl1, acc01);
        acc10 = MFMA16(ah1, bh0, acc10);
        acc10 = MFMA16(al1, bh0, acc10);
        acc10 = MFMA16(ah1, bl0, acc10);
        acc11 = MFMA16(ah1, bh1, acc11);
        acc11 = MFMA16(al1, bh1, acc11);
        acc11 = MFMA16(ah1, bl1, acc11);
        __syncthreads();
    }
    float* o = Cp + (size_t)kz * 512 * Nout;
    const int orow = (lane >> 4) * 4;
    #pragma unroll
    for (int r2 = 0; r2 < 4; ++r2) {
        o[(size_t)(m0+wm+orow+r2)*Nout      + n0+wn+fr]      = acc00[r2];
        o[(size_t)(m0+wm+orow+r2)*Nout      + n0+wn+16+fr]   = acc01[r2];
        o[(size_t)(m0+wm+16+orow+r2)*Nout   + n0+wn+fr]      = acc10[r2];
        o[(size_t)(m0+wm+16+orow+r2)*Nout   + n0+wn+16+fr]   = acc11[r2];
    }
}

// ---------------------------------------------------------------------------
// out-GEMM MFMA: A = [Q | Cx] select by kz (K=2048 split 4), B = Wout hi/lo
// ---------------------------------------------------------------------------
__global__ __launch_bounds__(256) void mfma_out_kernel(
    const ushort* __restrict__ Qh, const ushort* __restrict__ Ql,
    const ushort* __restrict__ Cxh, const ushort* __restrict__ Cxl,
    const ushort* __restrict__ Wh, const ushort* __restrict__ Wl,
    float* __restrict__ Fp)
{
    __shared__ alignas(16) ushort lA[2][64][40];
    __shared__ alignas(16) ushort lB[2][64][40];
    const int t = threadIdx.x;
    const int m0 = blockIdx.y * 64, n0 = blockIdx.x * 64, kz = blockIdx.z;
    const ushort* ah_p = (kz < 2) ? Qh : Cxh;
    const ushort* al_p = (kz < 2) ? Ql : Cxl;
    const int akoff = (kz & 1) * 512;
    const int bkoff = kz * 512;
    const int srow = t >> 2, skc = (t & 3) * 8;
    const int lane = t & 63, w = t >> 6;
    const int wm = (w >> 1) * 32, wn = (w & 1) * 32;
    const int fr = lane & 15, fg = (lane >> 4) * 8;

    f32x4 acc00 = {0,0,0,0}, acc01 = {0,0,0,0}, acc10 = {0,0,0,0}, acc11 = {0,0,0,0};

    for (int kk = 0; kk < 512; kk += 32) {
        uint4 va_h = *(const uint4*)(ah_p + (size_t)(m0+srow)*1024 + akoff + kk + skc);
        uint4 va_l = *(const uint4*)(al_p + (size_t)(m0+srow)*1024 + akoff + kk + skc);
        uint4 vb_h = *(const uint4*)(Wh   + (size_t)(n0+srow)*2048 + bkoff + kk + skc);
        uint4 vb_l = *(const uint4*)(Wl   + (size_t)(n0+srow)*2048 + bkoff + kk + skc);
        *(uint4*)&lA[0][srow][skc] = va_h;
        *(uint4*)&lA[1][srow][skc] = va_l;
        *(uint4*)&lB[0][srow][skc] = vb_h;
        *(uint4*)&lB[1][srow][skc] = vb_l;
        __syncthreads();
        bf16x8 ah0 = *(const bf16x8*)&lA[0][wm + fr     ][fg];
        bf16x8 ah1 = *(const bf16x8*)&lA[0][wm + 16 + fr][fg];
        bf16x8 al0 = *(const bf16x8*)&lA[1][wm + fr     ][fg];
        bf16x8 al1 = *(const bf16x8*)&lA[1][wm + 16 + fr][fg];
        bf16x8 bh0 = *(const bf16x8*)&lB[0][wn + fr     ][fg];
        bf16x8 bh1 = *(const bf16x8*)&lB[0][wn + 16 + fr][fg];
        bf16x8 bl0 = *(const bf16x8*)&lB[1][wn + fr     ][fg];
        bf16x8 bl1 = *(const bf16x8*)&lB[1][wn + 16 + fr][fg];
        acc00 = MFMA16(ah0, bh0, acc00);
        acc00 = MFMA16(al0, bh0, acc00);
        acc00 = MFMA16(ah0, bl0, acc00);
        acc01 = MFMA16(ah0, bh1, acc01);
        acc01 = MFMA16(al0, bh1, acc01);
        acc01 = MFMA16(ah0, bl1, acc01);
        acc10 = MFMA16(ah1, bh0, acc10);
        acc10 = MFMA16(al1, bh0, acc10);
        acc10 = MFMA16(ah1, bl0, acc10);
        acc11 = MFMA16(ah1, bh1, acc11);
        acc11 = MFMA16(al1, bh1, acc11);
        acc11 = MFMA16(ah1, bl1, acc11);
        __syncthreads();
    }
    float* o = Fp + (size_t)kz * 512 * 1024;
    const int orow = (lane >> 4) * 4;
    #pragma unroll
    for (int r2 = 0; r2 < 4; ++r2) {
        o[(size_t)(m0+wm+orow+r2)*1024    + n0+wn+fr]    = acc00[r2];
        o[(size_t)(m0+wm+orow+r2)*1024    + n0+wn+16+fr] = acc01[r2];
        o[(size_t)(m0+wm+16+orow+r2)*1024 + n0+wn+fr]    = acc10[r2];
        o[(size_t)(m0+wm+16+orow+r2)*1024 + n0+wn+16+fr] = acc11[r2];
    }
}

// ---------------------------------------------------------------------------
// Ea = exp2((p0+p1+bq)*2log2e)
// ---------------------------------------------------------------------------
__global__ __launch_bounds__(256) void exp_combine_kernel(
    const float* __restrict__ Ap, const float* __restrict__ bias,
    float* __restrict__ E)
{
    int i = blockIdx.x * 256 + threadIdx.x;
    float4 p0 = ((const float4*)Ap)[i];
    float4 p1 = ((const float4*)(Ap + (size_t)B_*TQ*NN))[i];
    float4 bb = ((const float4*)bias)[i & 255];
    float4 r;
    r.x = exp2f((p0.x + p1.x + bb.x) * K2F);
    r.y = exp2f((p0.y + p1.y + bb.y) * K2F);
    r.z = exp2f((p0.z + p1.z + bb.z) * K2F);
    r.w = exp2f((p0.w + p1.w + bb.w) * K2F);
    ((float4*)E)[i] = r;
}

// ---------------------------------------------------------------------------
// scores: Sp[nh][bq][k] = sum_{n in half} w[n]*rcp(1+Ea[bq,n]*e^{2*keys[bk,n]})
// keys exp'd on the fly during staging (saves Ek buffer + kernel).
// ---------------------------------------------------------------------------
__global__ __launch_bounds__(256) void score_partial_kernel(
    const float* __restrict__ Ea,   // [B*TQ, NN]
    const float* __restrict__ keys, // [B*TK, NN] raw
    const float* __restrict__ watt, // [NN]
    float* __restrict__ Sp)         // [2][B*TQ, TK]
{
    __shared__ float EaS[32][34];
    __shared__ float EkS[32][34];
    __shared__ float wS[32];
    const int tid = threadIdx.x;
    const int tx = tid & 15, ty = tid >> 4;
    const int kt = blockIdx.x;
    const int qt = blockIdx.y;
    const int bz = blockIdx.z;
    const int b = bz >> 1, nh = bz & 1;
    const int qrow0 = b*TQ + qt*32;
    const int krow0 = b*TK + kt*32;
    const int lr = tid >> 3;
    const int ln = (tid & 7) * 4;
    float acc[2][2] = {};
    const int nend = nh*512 + 512;
    for (int nb = nh*512; nb < nend; nb += 32) {
        float4 av = *(const float4*)(Ea   + (size_t)(qrow0 + lr)*NN + nb + ln);
        float4 kv = *(const float4*)(keys + (size_t)(krow0 + lr)*NN + nb + ln);
        kv.x = exp2f(kv.x * K2F); kv.y = exp2f(kv.y * K2F);
        kv.z = exp2f(kv.z * K2F); kv.w = exp2f(kv.w * K2F);
        EaS[ln+0][lr]=av.x; EaS[ln+1][lr]=av.y; EaS[ln+2][lr]=av.z; EaS[ln+3][lr]=av.w;
        EkS[ln+0][lr]=kv.x; EkS[ln+1][lr]=kv.y; EkS[ln+2][lr]=kv.z; EkS[ln+3][lr]=kv.w;
        if (tid < 32) wS[tid] = watt[nb + tid];
        __syncthreads();
        #pragma unroll
        for (int n = 0; n < 32; ++n) {
            float wn  = wS[n];
            float ea0 = EaS[n][ty*2],  ea1 = EaS[n][ty*2+1];
            float ek0 = EkS[n][tx*2],  ek1 = EkS[n][tx*2+1];
            acc[0][0] = fmaf(wn, __builtin_amdgcn_rcpf(fmaf(ea0, ek0, 1.0f)), acc[0][0]);
            acc[0][1] = fmaf(wn, __builtin_amdgcn_rcpf(fmaf(ea0, ek1, 1.0f)), acc[0][1]);
            acc[1][0] = fmaf(wn, __builtin_amdgcn_rcpf(fmaf(ea1, ek0, 1.0f)), acc[1][0]);
            acc[1][1] = fmaf(wn, __builtin_amdgcn_rcpf(fmaf(ea1, ek1, 1.0f)), acc[1][1]);
        }
        __syncthreads();
    }
    #pragma unroll
    for (int i = 0; i < 2; ++i) {
        int q = qt*32 + ty*2 + i;
        #pragma unroll
        for (int j = 0; j < 2; ++j) {
            int k = kt*32 + tx*2 + j;
            Sp[(size_t)nh*(B_*TQ*TK) + (size_t)(b*TQ + q)*TK + k] = acc[i][j];
        }
    }
}

// ---------------------------------------------------------------------------
// softmax over k of (-2*(S0+S1)); writes P f32 (output 1) + hi/lo bf16
// ---------------------------------------------------------------------------
__global__ __launch_bounds__(256) void softmax_kernel(
    const float* __restrict__ Sp, float* __restrict__ P,
    ushort* __restrict__ Ph, ushort* __restrict__ Pl)
{
    const int lane = threadIdx.x & 63;
    const int wid  = threadIdx.x >> 6;
    const int row  = blockIdx.x * 4 + wid;
    const float* s0 = Sp + (size_t)row * TK;
    const float* s1 = Sp + (size_t)(B_*TQ*TK) + (size_t)row * TK;
    float v[8];
    float m = -3.4e38f;
    #pragma unroll
    for (int j = 0; j < 8; ++j) {
        int k = lane + j*64;
        v[j] = -2.0f * (s0[k] + s1[k]);
        m = fmaxf(m, v[j]);
    }
    #pragma unroll
    for (int off = 32; off; off >>= 1) m = fmaxf(m, __shfl_xor(m, off, 64));
    float sum = 0.f;
    #pragma unroll
    for (int j = 0; j < 8; ++j) { v[j] = exp2f((v[j] - m) * LOG2EF); sum += v[j]; }
    #pragma unroll
    for (int off = 32; off; off >>= 1) sum += __shfl_xor(sum, off, 64);
    float inv = 1.0f / sum;
    #pragma unroll
    for (int j = 0; j < 8; ++j) {
        int k = lane + j*64;
        float pv = v[j] * inv;
        P[(size_t)row * TK + k] = pv;
        ushort h, l; split2(pv, h, l);
        Ph[(size_t)row * TK + k] = h;
        Pl[(size_t)row * TK + k] = l;
    }
}

// ---------------------------------------------------------------------------
// Cx = Ep0+Ep1 -> hi/lo bf16 only (f32 Cx not needed downstream)
// ---------------------------------------------------------------------------
__global__ __launch_bounds__(256) void combine_cvt_kernel(
    const float* __restrict__ Ep, ushort* __restrict__ Ch, ushort* __restrict__ Cl)
{
    int i = blockIdx.x * 256 + threadIdx.x;      // float4 index
    float4 p0 = ((const float4*)Ep)[i];
    float4 p1 = ((const float4*)(Ep + (size_t)B_*TQ*VS))[i];
    float4 s = {p0.x+p1.x, p0.y+p1.y, p0.z+p1.z, p0.w+p1.w};
    ushort4 hh, ll;
    split2(s.x, hh.x, ll.x); split2(s.y, hh.y, ll.y);
    split2(s.z, hh.z, ll.z); split2(s.w, hh.w, ll.w);
    ((ushort4*)Ch)[i] = hh;
    ((ushort4*)Cl)[i] = ll;
}

// ---------------------------------------------------------------------------
// out = tanh(sum Fp + bias)
// ---------------------------------------------------------------------------
__global__ __launch_bounds__(256) void tanh_combine_kernel(
    const float* __restrict__ Fp, const float* __restrict__ bias,
    float* __restrict__ out)
{
    int i = blockIdx.x * 256 + threadIdx.x;
    const size_t S = (size_t)B_*TQ*OS;
    float4 p0 = ((const float4*)Fp)[i];
    float4 p1 = ((const float4*)(Fp + S))[i];
    float4 p2 = ((const float4*)(Fp + 2*S))[i];
    float4 p3 = ((const float4*)(Fp + 3*S))[i];
    float4 bb = ((const float4*)bias)[i & 255];
    float4 r;
    r.x = tanhf(p0.x + p1.x + p2.x + p3.x + bb.x);
    r.y = tanhf(p0.y + p1.y + p2.y + p3.y + bb.y);
    r.z = tanhf(p0.z + p1.z + p2.z + p3.z + bb.z);
    r.w = tanhf(p0.w + p1.w + p2.w + p3.w + bb.w);
    ((float4*)out)[i] = r;
}

// ---------------------------------------------------------------------------
extern "C" void kernel_launch(void* const* d_in, const int* in_sizes, int n_in,
                              void* d_out, int out_size, void* d_ws, size_t ws_size,
                              hipStream_t stream)
{
    const float* query  = (const float*)d_in[0];   // [4,128,1024]
    const float* keys   = (const float*)d_in[1];   // [4,512,1024]
    const float* values = (const float*)d_in[2];   // [4,512,1024]
    const float* Wq     = (const float*)d_in[3];   // [1024,1024]
    const float* bq     = (const float*)d_in[4];   // [1024]
    const float* watt   = (const float*)d_in[5];   // [1024]
    // d_in[6] = b_att: dropped (softmax shift-invariance)
    const float* Wout   = (const float*)d_in[7];   // [1024,2048]
    const float* bout   = (const float*)d_in[8];   // [1024]

    float* out = (float*)d_out;                    // output 0 (524288 f32)
    float* P   = out + (size_t)B_*TQ*OS;           // output 1 (262144 f32)

    // ws layout (byte offsets, 32 MB total), phase-disjoint aliasing:
    //  [ 0, 2M): Wqh/Wql (ph1-2)          | [0,8M): Fp (ph8-9)
    //  [ 4, 8M): Ap f32 partials (ph2-3)
    //  [ 8,10M): Qh/Ql (ph1-8)
    //  [10,18M): Woh/Wol (ph1-8)
    //  [18,26M): Vth/Vtl (ph1-6)
    //  [26,28M): Ea (ph3-4) | [26,30M): Ep (ph6-7)
    //  [28,30M): Sp (ph4-5)
    //  [30,31M): Ph/Pl (ph5-6) | [30,32M): Cxh/Cxl (ph7-8)
    char* base = (char*)d_ws;
    const size_t MB = 1u << 20;
    ushort* Wqh = (ushort*)(base + 0*MB);
    ushort* Wql = (ushort*)(base + 2*MB);
    float*  Ap  = (float*) (base + 4*MB);
    float*  Fp  = (float*) (base + 0*MB);
    ushort* Qh  = (ushort*)(base + 8*MB);
    ushort* Ql  = (ushort*)(base + 9*MB);
    ushort* Woh = (ushort*)(base + 10*MB);
    ushort* Wol = (ushort*)(base + 14*MB);
    ushort* Vth = (ushort*)(base + 18*MB);
    ushort* Vtl = (ushort*)(base + 22*MB);
    float*  Ea  = (float*) (base + 26*MB);
    float*  Ep  = (float*) (base + 26*MB);
    float*  Sp  = (float*) (base + 28*MB);
    ushort* Ph  = (ushort*)(base + 30*MB);
    ushort* Pl  = (ushort*)(base + 30*MB + 512*1024);
    ushort* Cxh = (ushort*)(base + 30*MB);
    ushort* Cxl = (ushort*)(base + 31*MB);

    // [1] conversions
    cvt_split_kernel<<<dim3(512),  dim3(256), 0, stream>>>(query, Qh, Ql);
    cvt_split_kernel<<<dim3(1024), dim3(256), 0, stream>>>(Wq, Wqh, Wql);
    cvt_split_kernel<<<dim3(2048), dim3(256), 0, stream>>>(Wout, Woh, Wol);
    cvt_transpose_v_kernel<<<dim3(16, 8, 4), dim3(256), 0, stream>>>(values, Vth, Vtl);
    // [2] A-GEMM: Aq partials = Q @ Wq^T  (K=1024 split 2)
    mfma_nt_kernel<<<dim3(16, 8, 2), dim3(256), 0, stream>>>(
        Qh, Ql, Wqh, Wql, Ap, 1024, 1024, 1024, 512, 0);
    // [3] Ea = e^{2*(Aq+bq)}
    exp_combine_kernel<<<dim3(512), dim3(256), 0, stream>>>(Ap, bq, Ea);
    // [4] scores
    score_partial_kernel<<<dim3(16, 4, 8), dim3(256), 0, stream>>>(Ea, keys, watt, Sp);
    // [5] softmax -> P (output 1) + Ph/Pl
    softmax_kernel<<<dim3(128), dim3(256), 0, stream>>>(Sp, P, Ph, Pl);
    // [6] PV: context partials = P @ V  (per-batch, K=512 split 2)
    mfma_nt_kernel<<<dim3(16, 8, 2), dim3(256), 0, stream>>>(
        Ph, Pl, Vth, Vtl, Ep, 512, 512, 1024, 256, VS*TK);
    // [7] Cx hi/lo
    combine_cvt_kernel<<<dim3(512), dim3(256), 0, stream>>>(Ep, Cxh, Cxl);
    // [8] out-GEMM partials (K=2048 split 4)
    mfma_out_kernel<<<dim3(16, 8, 4), dim3(256), 0, stream>>>(
        Qh, Ql, Cxh, Cxl, Woh, Wol, Fp);
    // [9] out = tanh(sum + bout)
    tanh_combine_kernel<<<dim3(512), dim3(256), 0, stream>>>(Fp, bout, out);
}